// Round 1
// baseline (717.540 us; speedup 1.0000x reference)
//
#include <hip/hip_runtime.h>
#include <hip/hip_bf16.h>

// Problem: B=8, N=1024, C=256, R=16
//   qh = q @ Wq^T + bq ; kh = k @ Wk^T + bk       (B,N,C)
//   scores = qh @ kh^T / 16                        (B,N,N)
//   out[b,r,i,j] = scores[b,i,j] * R_map[i,j,r]    (B,R,N,N) fp32
//
// Stage 1: proj_kernel -> qh,kh as bf16 in d_ws (4 MiB each)
// Stage 2: score_mul_kernel -> 64x64 score tile via MFMA, LDS relayout,
//          fused multiply with R_map, 512 MiB coalesced store.

typedef float  floatx4 __attribute__((ext_vector_type(4)));
typedef short  shortx8 __attribute__((ext_vector_type(8)));

__device__ __forceinline__ short f2bf(float f) {
    // round-to-nearest-even f32 -> bf16 (inputs are finite; no NaN handling)
    unsigned int u = __builtin_bit_cast(unsigned int, f);
    u += 0x7fffu + ((u >> 16) & 1u);
    return (short)(u >> 16);
}

// ---------------- Stage 1: Q/K projection, fp32 in -> bf16 out ----------------
// grid (512, 16, 2), block 64 (one wave). z=0: Q, z=1: K.
// Tile: 16x16 output per wave, K=256 in 8 MFMA steps.
__global__ __launch_bounds__(64) void proj_kernel(
    const float* __restrict__ Xq, const float* __restrict__ Wq, const float* __restrict__ bq,
    const float* __restrict__ Xk, const float* __restrict__ Wk, const float* __restrict__ bk,
    short* __restrict__ qh, short* __restrict__ kh)
{
    const float* X; const float* W; const float* bias; short* outp;
    if (blockIdx.z == 0) { X = Xq; W = Wq; bias = bq; outp = qh; }
    else                 { X = Xk; W = Wk; bias = bk; outp = kh; }

    const int lane  = threadIdx.x;
    const int row16 = lane & 15;
    const int quad  = lane >> 4;
    const int m0 = blockIdx.x * 16;   // row tile in (B*N)=8192
    const int c0 = blockIdx.y * 16;   // col tile in C=256

    const float* xr = X + (size_t)(m0 + row16) * 256 + quad * 8;
    const float* wr = W + (size_t)(c0 + row16) * 256 + quad * 8;

    floatx4 acc = {0.f, 0.f, 0.f, 0.f};
#pragma unroll
    for (int k = 0; k < 256; k += 32) {
        float4 a0 = *(const float4*)(xr + k);
        float4 a1 = *(const float4*)(xr + k + 4);
        float4 b0 = *(const float4*)(wr + k);
        float4 b1 = *(const float4*)(wr + k + 4);
        shortx8 af = { f2bf(a0.x), f2bf(a0.y), f2bf(a0.z), f2bf(a0.w),
                       f2bf(a1.x), f2bf(a1.y), f2bf(a1.z), f2bf(a1.w) };
        shortx8 bf = { f2bf(b0.x), f2bf(b0.y), f2bf(b0.z), f2bf(b0.w),
                       f2bf(b1.x), f2bf(b1.y), f2bf(b1.z), f2bf(b1.w) };
        acc = __builtin_amdgcn_mfma_f32_16x16x32_bf16(af, bf, acc, 0, 0, 0);
    }

    // C/D layout: col = lane&15 (c), row = quad*4+reg (m)
    const int c = c0 + row16;
    const float bv = bias[c];
#pragma unroll
    for (int r = 0; r < 4; r++) {
        const int m = m0 + quad * 4 + r;
        outp[(size_t)m * 256 + c] = f2bf(acc[r] + bv);
    }
}

// ---------------- Stage 2: fused QK^T * (1/16) * R_map -> out ----------------
// grid (8, 16, 16): x=b (fastest: 8 blocks sharing an R tile run adjacently),
// y = j-tile (64), z = i-tile (64). Block 256 = 4 waves.
// Wave w computes score rows [i0+16w, i0+16w+16) x cols [j0, j0+64).
__global__ __launch_bounds__(256) void score_mul_kernel(
    const short* __restrict__ qh, const short* __restrict__ kh,
    const float* __restrict__ Rm, float* __restrict__ out)
{
    const int b  = blockIdx.x;
    const int j0 = blockIdx.y * 64;
    const int i0 = blockIdx.z * 64;

    const int tid   = threadIdx.x;
    const int wave  = tid >> 6;
    const int lane  = tid & 63;
    const int row16 = lane & 15;
    const int quad  = lane >> 4;

    __shared__ float s_lds[64 * 68];   // stride 68 -> conflict-light write

    // ---- compute phase: 4 MFMA column-tiles per wave over K=256 ----
    const short* qbase = qh + ((size_t)(b * 1024 + i0 + wave * 16 + row16)) * 256 + quad * 8;
    const short* kbase = kh + ((size_t)(b * 1024 + j0 + row16)) * 256 + quad * 8;

    floatx4 acc[4];
#pragma unroll
    for (int nt = 0; nt < 4; nt++) acc[nt] = floatx4{0.f, 0.f, 0.f, 0.f};

#pragma unroll
    for (int k = 0; k < 256; k += 32) {
        shortx8 af = *(const shortx8*)(qbase + k);
#pragma unroll
        for (int nt = 0; nt < 4; nt++) {
            shortx8 bf = *(const shortx8*)(kbase + (size_t)nt * 16 * 256 + k);
            acc[nt] = __builtin_amdgcn_mfma_f32_16x16x32_bf16(af, bf, acc[nt], 0, 0, 0);
        }
    }

    const float inv = 0.0625f;  // 1/sqrt(256)
#pragma unroll
    for (int nt = 0; nt < 4; nt++) {
#pragma unroll
        for (int r = 0; r < 4; r++) {
            const int il = wave * 16 + quad * 4 + r;   // local i
            const int jl = nt * 16 + row16;            // local j
            s_lds[il * 68 + jl] = acc[nt][r] * inv;
        }
    }
    __syncthreads();

    // ---- multiply phase: thread owns column j = tid&63; wave w owns rows w*16.. ----
    const int j = tid & 63;
    const int w = tid >> 6;
    const size_t NN = (size_t)1024 * 1024;

#pragma unroll 2
    for (int ii = 0; ii < 16; ii++) {
        const int il = w * 16 + ii;
        const int i  = i0 + il;
        const float s = s_lds[il * 68 + j];
        const float* rp = Rm + ((size_t)i * 1024 + (j0 + j)) * 16;
        float4 r0 = *(const float4*)(rp);
        float4 r1 = *(const float4*)(rp + 4);
        float4 r2 = *(const float4*)(rp + 8);
        float4 r3 = *(const float4*)(rp + 12);
        float* op = out + ((size_t)(b * 16) * 1024 + i) * 1024 + (j0 + j);
        op[0 * NN]  = s * r0.x;  op[1 * NN]  = s * r0.y;
        op[2 * NN]  = s * r0.z;  op[3 * NN]  = s * r0.w;
        op[4 * NN]  = s * r1.x;  op[5 * NN]  = s * r1.y;
        op[6 * NN]  = s * r1.z;  op[7 * NN]  = s * r1.w;
        op[8 * NN]  = s * r2.x;  op[9 * NN]  = s * r2.y;
        op[10 * NN] = s * r2.z;  op[11 * NN] = s * r2.w;
        op[12 * NN] = s * r3.x;  op[13 * NN] = s * r3.y;
        op[14 * NN] = s * r3.z;  op[15 * NN] = s * r3.w;
    }
}

extern "C" void kernel_launch(void* const* d_in, const int* in_sizes, int n_in,
                              void* d_out, int out_size, void* d_ws, size_t ws_size,
                              hipStream_t stream) {
    const float* q   = (const float*)d_in[0];  // (8,1024,256)
    const float* k   = (const float*)d_in[1];  // (8,1024,256)
    const float* Wq  = (const float*)d_in[2];  // (256,256)
    const float* bq  = (const float*)d_in[3];  // (256)
    const float* Wk  = (const float*)d_in[4];  // (256,256)
    const float* bk  = (const float*)d_in[5];  // (256)
    const float* Rm  = (const float*)d_in[6];  // (1024,1024,16)
    float* out = (float*)d_out;                // (8,16,1024,1024)

    short* qh = (short*)d_ws;                         // 8192*256 bf16 = 4 MiB
    short* kh = (short*)d_ws + (size_t)8192 * 256;    // next 4 MiB

    dim3 pgrid(512, 16, 2);
    proj_kernel<<<pgrid, 64, 0, stream>>>(q, Wq, bq, k, Wk, bk, qh, kh);

    dim3 sgrid(8, 16, 16);
    score_mul_kernel<<<sgrid, 256, 0, stream>>>(qh, kh, Rm, out);
}